// Round 3
// baseline (1861.704 us; speedup 1.0000x reference)
//
#include <hip/hip_runtime.h>
#include <hip/hip_bf16.h>
#include <stdint.h>
#include <stddef.h>

// TFT block on MI355X. B=64 T=384 V=12 D=256 H=4 DK=64.
// R3: inputs/outputs are FLOAT32 (per reference). MFMA compute in bf16:
// f32 A-operands converted during LDS staging; weights converted in prep.
typedef __bf16 bf16;
typedef __bf16 bf16x8 __attribute__((ext_vector_type(8)));
typedef float  f32x4  __attribute__((ext_vector_type(4)));

#define BTR 24576   // B*T rows
#define EPI_BIAS 1
#define EPI_CVEC 2
#define EPI_ELU  4
#define EPI_ATTN 8

// ---------------- 128x128 tile bf16 MFMA GEMM, C[m][n] = sum_k A[m][k]*Bt[n][k] ----------------
// AF32: A operand is float32 in global (converted to bf16 at staging). CF32: C stored as float.
// grid = (N/128, M/128, Z). batch: h=z/zdiv, b=z%zdiv.
template<int EPI, bool AF32, bool CF32>
__global__ __launch_bounds__(256, 2)
void gemm_kernel(const void* __restrict__ Av, int lda, long sAh, long sAb,
                 const bf16* __restrict__ Bt, int ldb, long sBh, long sBb,
                 void* __restrict__ Cv, int ldc, long sC,
                 int K, int zdiv,
                 const float* __restrict__ bias, const float* __restrict__ cvec)
{
  __shared__ __align__(16) bf16 As[128 * 32];
  __shared__ __align__(16) bf16 Bs[128 * 32];

  const int tid  = threadIdx.x;
  const int wave = tid >> 6, lane = tid & 63;
  const int wr = wave >> 1, wc = wave & 1;         // 2x2 waves, 64x64 each
  const int quad = lane >> 4, l16 = lane & 15;

  const int z  = blockIdx.z;
  const int hh = z / zdiv, bb = z % zdiv;
  const float* AbF = nullptr; const bf16* AbH = nullptr;
  if constexpr (AF32) AbF = (const float*)Av + (long)hh * sAh + (long)bb * sAb;
  else                AbH = (const bf16*)Av  + (long)hh * sAh + (long)bb * sAb;
  const bf16* Bb = Bt + (long)hh * sBh + (long)bb * sBb;
  float* CbF = nullptr; bf16* CbH = nullptr;
  if constexpr (CF32) CbF = (float*)Cv + (long)z * sC;
  else                CbH = (bf16*)Cv  + (long)z * sC;

  const int rowBase = blockIdx.y * 128;
  const int colBase = blockIdx.x * 128;

  f32x4 acc[4][4];
#pragma unroll
  for (int i = 0; i < 4; ++i)
#pragma unroll
    for (int j = 0; j < 4; ++j) { acc[i][j][0]=0.f; acc[i][j][1]=0.f; acc[i][j][2]=0.f; acc[i][j][3]=0.f; }

  const int r0 = tid >> 2, kc = tid & 3;           // bf16-A / B decode: 16B chunks, 4 per 32-elem row
  const int r1 = tid >> 1, kh = (tid & 1) * 16;    // f32-A decode: 64B half-rows
  const int arow = (wr * 64 + l16) * 32 + quad * 8;
  const int brow = (wc * 64 + l16) * 32 + quad * 8;

  for (int k0 = 0; k0 < K; k0 += 32) {
    bf16x8 a0, a1;
    if constexpr (AF32) {
      const float* p = AbF + (size_t)(rowBase + r1) * lda + k0 + kh;
      f32x4 f0 = *(const f32x4*)(p);
      f32x4 f1 = *(const f32x4*)(p + 4);
      f32x4 f2 = *(const f32x4*)(p + 8);
      f32x4 f3 = *(const f32x4*)(p + 12);
#pragma unroll
      for (int e = 0; e < 4; ++e) {
        a0[e] = (bf16)f0[e]; a0[4 + e] = (bf16)f1[e];
        a1[e] = (bf16)f2[e]; a1[4 + e] = (bf16)f3[e];
      }
    } else {
      a0 = *(const bf16x8*)(AbH + (size_t)(rowBase + r0)      * lda + k0 + kc * 8);
      a1 = *(const bf16x8*)(AbH + (size_t)(rowBase + 64 + r0) * lda + k0 + kc * 8);
    }
    bf16x8 b0 = *(const bf16x8*)(Bb + (size_t)(colBase + r0)      * ldb + k0 + kc * 8);
    bf16x8 b1 = *(const bf16x8*)(Bb + (size_t)(colBase + 64 + r0) * ldb + k0 + kc * 8);
    __syncthreads();   // previous iteration's ds_reads complete before overwrite
    if constexpr (AF32) {
      *(bf16x8*)(As + r1 * 32 + kh)     = a0;
      *(bf16x8*)(As + r1 * 32 + kh + 8) = a1;
    } else {
      *(bf16x8*)(As +        r0 * 32 + kc * 8) = a0;
      *(bf16x8*)(As + 2048 + r0 * 32 + kc * 8) = a1;
    }
    *(bf16x8*)(Bs +        r0 * 32 + kc * 8) = b0;
    *(bf16x8*)(Bs + 2048 + r0 * 32 + kc * 8) = b1;
    __syncthreads();

    bf16x8 af[4], bfv[4];
#pragma unroll
    for (int mi = 0; mi < 4; ++mi) af[mi]  = *(const bf16x8*)(As + arow + mi * 512);
#pragma unroll
    for (int ni = 0; ni < 4; ++ni) bfv[ni] = *(const bf16x8*)(Bs + brow + ni * 512);
#pragma unroll
    for (int mi = 0; mi < 4; ++mi)
#pragma unroll
      for (int ni = 0; ni < 4; ++ni)
        acc[mi][ni] = __builtin_amdgcn_mfma_f32_16x16x32_bf16(af[mi], bfv[ni], acc[mi][ni], 0, 0, 0);
  }

  // epilogue. C/D layout: col = lane&15, row = quad*4 + reg  [m89-verified]
  const int bctx = (EPI & EPI_CVEC) ? (rowBase / 384) : 0;  // 128-row tile never crosses a b boundary
#pragma unroll
  for (int mi = 0; mi < 4; ++mi) {
#pragma unroll
    for (int ni = 0; ni < 4; ++ni) {
      const int row0 = rowBase + wr * 64 + mi * 16 + quad * 4;
      const int col  = colBase + wc * 64 + ni * 16 + l16;
      float bv = (EPI & EPI_BIAS) ? bias[col] : 0.f;
      float cv = (EPI & EPI_CVEC) ? cvec[bctx * 256 + col] : 0.f;
#pragma unroll
      for (int r = 0; r < 4; ++r) {
        float v = acc[mi][ni][r] + bv + cv;
        if (EPI & EPI_ELU)  v = v > 0.f ? v : __expf(v) - 1.f;
        if (EPI & EPI_ATTN) { v *= 0.125f; if (col > row0 + r) v = -1e9f; }
        if constexpr (CF32) CbF[(size_t)(row0 + r) * ldc + col] = v;
        else                CbH[(size_t)(row0 + r) * ldc + col] = (bf16)v;
      }
    }
  }
}

// ---------------- prep: all weight transposes / pads (f32 -> bf16), one launch ----------------
__global__ void prep_kernel(
    const float* fgW1, const float* fgW2, const float* fgWg, const float* fgbg,
    const float* fgWs, const float* fgbs,
    const float* svW1, const float* svW2, const float* svWg,
    const float* enW1, const float* enW2, const float* enWg,
    const float* Wq, const float* Wk, const float* Wv, const float* Wo,
    bf16* fgW1T, bf16* fgW2T, bf16* fgWgPT, float* bgPad,
    bf16* fgWsPT, float* bsPad,
    bf16* svW1T, bf16* svW2T, bf16* svWgT,
    bf16* enW1T, bf16* enW2T, bf16* enWgT,
    bf16* WqkvT, bf16* WoT)
{
  long i = (long)blockIdx.x * 256 + threadIdx.x;
  if (i < 786432) { int n = i / 3072, k = i % 3072; fgW1T[i] = (bf16)fgW1[(size_t)k * 256 + n]; return; } i -= 786432;
  if (i < 65536)  { int n = i >> 8, k = i & 255; fgW2T[i] = (bf16)fgW2[k * 256 + n]; return; } i -= 65536;
  if (i < 32768)  { int n = i >> 8, k = i & 255; fgWgPT[i] = (n < 24) ? (bf16)fgWg[k * 24 + n] : (bf16)0.f; return; } i -= 32768;
  if (i < 128)    { bgPad[i] = (i < 24) ? fgbg[i] : 0.f; return; } i -= 128;
  if (i < 393216) { int n = i / 3072, k = i % 3072; fgWsPT[i] = (n < 12) ? (bf16)fgWs[(size_t)k * 12 + n] : (bf16)0.f; return; } i -= 393216;
  if (i < 128)    { bsPad[i] = (i < 12) ? fgbs[i] : 0.f; return; } i -= 128;
  if (i < 786432) { long v = i >> 16, r = i & 65535; int n = r >> 8, k = r & 255; svW1T[i] = (bf16)svW1[(v << 16) + k * 256 + n]; return; } i -= 786432;
  if (i < 786432) { long v = i >> 16, r = i & 65535; int n = r >> 8, k = r & 255; svW2T[i] = (bf16)svW2[(v << 16) + k * 256 + n]; return; } i -= 786432;
  if (i < 1572864){ long v = i >> 17, r = i & 131071; int n = r >> 8, k = r & 255; svWgT[i] = (bf16)svWg[(v << 17) + k * 512 + n]; return; } i -= 1572864;
  if (i < 65536)  { int n = i >> 8, k = i & 255; enW1T[i] = (bf16)enW1[k * 256 + n]; return; } i -= 65536;
  if (i < 65536)  { int n = i >> 8, k = i & 255; enW2T[i] = (bf16)enW2[k * 256 + n]; return; } i -= 65536;
  if (i < 131072) { int n = i >> 8, k = i & 255; enWgT[i] = (bf16)enWg[k * 512 + n]; return; } i -= 131072;
  if (i < 163840) { int n = i >> 8, k = i & 255; float val;
                    if (n < 256)      val = Wq[(n >> 6) * 16384 + k * 64 + (n & 63)];
                    else if (n < 512) { int nn = n - 256; val = Wk[(nn >> 6) * 16384 + k * 64 + (nn & 63)]; }
                    else if (n < 576) val = Wv[k * 64 + (n - 512)];
                    else              val = 0.f;
                    WqkvT[i] = (bf16)val; return; } i -= 163840;
  if (i < 16384)  { int n = i >> 6, k = i & 63; WoT[i] = (bf16)Wo[k * 256 + n]; return; }
}

// ---------------- cvec[b][n] = context[b] @ Wc  (fg / en), all f32 ----------------
__global__ void cvec_kernel(const float* __restrict__ ctx, const float* __restrict__ WcFg,
                            const float* __restrict__ WcEn, float* __restrict__ outFg,
                            float* __restrict__ outEn) {
  int b = blockIdx.x, n = threadIdx.x;
  const float* Wc = blockIdx.y ? WcEn : WcFg;
  float* o = blockIdx.y ? outEn : outFg;
  float acc = 0.f;
  for (int d = 0; d < 256; ++d) acc += ctx[b * 256 + d] * Wc[d * 256 + n];
  o[b * 256 + n] = acc;
}

// ---------------- gate12: gated = a * sigmoid(gate) from padded g ----------------
__global__ void gate12_kernel(const bf16* __restrict__ GPAD, float* __restrict__ gated) {
  int i = blockIdx.x * 256 + threadIdx.x;
  if (i >= BTR * 12) return;
  int r = i / 12, j = i % 12;
  float a = (float)GPAD[(size_t)r * 128 + j];
  float g = (float)GPAD[(size_t)r * 128 + 12 + j];
  gated[i] = a / (1.f + __expf(-g));
}

// ---------------- lnsm12: w = softmax(LN(skip + gated)) over V=12 ----------------
__global__ void lnsm12_kernel(const bf16* __restrict__ SK, const float* __restrict__ gated,
                              const float* __restrict__ lng, const float* __restrict__ lnb,
                              float* __restrict__ w) {
  int r = blockIdx.x * 256 + threadIdx.x;
  if (r >= BTR) return;
  float y[12]; float m = 0.f;
#pragma unroll
  for (int j = 0; j < 12; ++j) { y[j] = (float)SK[(size_t)r * 128 + j] + gated[r * 12 + j]; m += y[j]; }
  m *= (1.f / 12.f);
  float var = 0.f;
#pragma unroll
  for (int j = 0; j < 12; ++j) { float d = y[j] - m; var += d * d; }
  var *= (1.f / 12.f);
  float rstd = rsqrtf(var + 1e-5f);
  float mx = -1e30f;
#pragma unroll
  for (int j = 0; j < 12; ++j) { y[j] = (y[j] - m) * rstd * lng[j] + lnb[j]; mx = fmaxf(mx, y[j]); }
  float s = 0.f;
#pragma unroll
  for (int j = 0; j < 12; ++j) { y[j] = __expf(y[j] - mx); s += y[j]; }
  float inv = 1.f / s;
#pragma unroll
  for (int j = 0; j < 12; ++j) w[r * 12 + j] = y[j] * inv;
}

// ---------------- block (256-thr) reduce of two sums ----------------
__device__ __forceinline__ void block_sum2(float a, float b, float& oa, float& ob) {
#pragma unroll
  for (int o = 32; o; o >>= 1) { a += __shfl_xor(a, o); b += __shfl_xor(b, o); }
  __shared__ float ra[4], rb[4];
  int w = threadIdx.x >> 6;
  if ((threadIdx.x & 63) == 0) { ra[w] = a; rb[w] = b; }
  __syncthreads();
  oa = ra[0] + ra[1] + ra[2] + ra[3];
  ob = rb[0] + rb[1] + rb[2] + rb[3];
  __syncthreads();
}

// ---------------- per-variable GRN tail: gating + LN + weighted accumulate into sel ----------------
__global__ __launch_bounds__(256)
void selacc_kernel(const bf16* __restrict__ G, const float* __restrict__ xv,
                   const float* __restrict__ w, const float* __restrict__ lng,
                   const float* __restrict__ lnb, float* __restrict__ sel,
                   bf16* __restrict__ selb, int v, int isLast) {
  int r = blockIdx.x, d = threadIdx.x;
  float a = (float)G[(size_t)r * 512 + d];
  float g = (float)G[(size_t)r * 512 + 256 + d];
  float gated = a / (1.f + __expf(-g));
  float y = xv[(size_t)r * 3072 + d] + gated;
  float s1, s2;
  block_sum2(y, y * y, s1, s2);
  float mean = s1 * (1.f / 256.f);
  float var = s2 * (1.f / 256.f) - mean * mean;
  float norm = (y - mean) * rsqrtf(var + 1e-5f);
  float val = norm * lng[d] + lnb[d];
  float snew = w[r * 12 + v] * val + (v == 0 ? 0.f : sel[(size_t)r * 256 + d]);
  if (isLast) selb[(size_t)r * 256 + d] = (bf16)snew;
  else        sel[(size_t)r * 256 + d] = snew;
}

// ---------------- enrichment GRN tail: gating + LN -> enr (bf16) ----------------
__global__ __launch_bounds__(256)
void enrln_kernel(const bf16* __restrict__ G, const bf16* __restrict__ skip,
                  const float* __restrict__ lng, const float* __restrict__ lnb,
                  bf16* __restrict__ out) {
  int r = blockIdx.x, d = threadIdx.x;
  float a = (float)G[(size_t)r * 512 + d];
  float g = (float)G[(size_t)r * 512 + 256 + d];
  float gated = a / (1.f + __expf(-g));
  float y = (float)skip[(size_t)r * 256 + d] + gated;
  float s1, s2;
  block_sum2(y, y * y, s1, s2);
  float mean = s1 * (1.f / 256.f);
  float var = s2 * (1.f / 256.f) - mean * mean;
  float norm = (y - mean) * rsqrtf(var + 1e-5f);
  out[(size_t)r * 256 + d] = (bf16)(norm * lng[d] + lnb[d]);
}

// ---------------- Pbar[b,q,:] = (1/4) sum_h softmax(S[h,b,q,:]) ----------------
__global__ __launch_bounds__(384)
void softmax_avg_kernel(const bf16* __restrict__ S, bf16* __restrict__ P) {
  const int bq = blockIdx.x;
  const int b = bq / 384, q = bq % 384;
  const int j = threadIdx.x;
  const int w = j >> 6;
  __shared__ float red[6];
  float pb = 0.f;
  for (int h = 0; h < 4; ++h) {
    float s = (float)S[((size_t)((h * 64 + b) * 384 + q)) * 384 + j];
    float m = s;
#pragma unroll
    for (int o = 32; o; o >>= 1) m = fmaxf(m, __shfl_xor(m, o));
    if ((j & 63) == 0) red[w] = m;
    __syncthreads();
    m = fmaxf(fmaxf(fmaxf(red[0], red[1]), fmaxf(red[2], red[3])), fmaxf(red[4], red[5]));
    __syncthreads();
    float e = __expf(s - m);
    float l = e;
#pragma unroll
    for (int o = 32; o; o >>= 1) l += __shfl_xor(l, o);
    if ((j & 63) == 0) red[w] = l;
    __syncthreads();
    l = red[0] + red[1] + red[2] + red[3] + red[4] + red[5];
    __syncthreads();
    pb += e / l;
  }
  P[(size_t)bq * 384 + j] = (bf16)(0.25f * pb);
}

// ---------------- UT[b][d][t] = U[b*384+t][d] ----------------
__global__ void transpose_u_kernel(const bf16* __restrict__ U, bf16* __restrict__ UT) {
  int t = blockIdx.x, b = blockIdx.y, d = threadIdx.x;
  UT[((size_t)b * 256 + d) * 384 + t] = U[((size_t)b * 384 + t) * 256 + d];
}

// ================= host side =================
template<int EPI, bool AF32, bool CF32>
static inline void rungemm(hipStream_t s,
    const void* A, int lda, const bf16* Bt, int ldb, void* C, int ldc,
    int M, int N, int K,
    const float* bias = nullptr, const float* cvec = nullptr,
    int Z = 1, int zdiv = 1,
    long sAh = 0, long sAb = 0, long sBh = 0, long sBb = 0, long sC = 0)
{
  dim3 grid(N / 128, M / 128, Z);
  gemm_kernel<EPI, AF32, CF32><<<grid, 256, 0, s>>>(A, lda, sAh, sAb, Bt, ldb, sBh, sBb, C, ldc, sC, K, zdiv, bias, cvec);
}

extern "C" void kernel_launch(void* const* d_in, const int* in_sizes, int n_in,
                              void* d_out, int out_size, void* d_ws, size_t ws_size,
                              hipStream_t stream)
{
  (void)in_sizes; (void)n_in; (void)out_size;
  const float* x      = (const float*)d_in[0];
  const float* ctx    = (const float*)d_in[1];
  const float* fg_W1  = (const float*)d_in[2];
  const float* fg_b1  = (const float*)d_in[3];
  const float* fg_Wc  = (const float*)d_in[4];
  const float* fg_W2  = (const float*)d_in[5];
  const float* fg_b2  = (const float*)d_in[6];
  const float* fg_Wg  = (const float*)d_in[7];
  const float* fg_bg  = (const float*)d_in[8];
  const float* fg_Ws  = (const float*)d_in[9];
  const float* fg_bs  = (const float*)d_in[10];
  const float* fg_lng = (const float*)d_in[11];
  const float* fg_lnb = (const float*)d_in[12];
  const float* sv_W1  = (const float*)d_in[13];
  const float* sv_b1  = (const float*)d_in[14];
  const float* sv_W2  = (const float*)d_in[15];
  const float* sv_b2  = (const float*)d_in[16];
  const float* sv_Wg  = (const float*)d_in[17];
  const float* sv_bg  = (const float*)d_in[18];
  const float* sv_lng = (const float*)d_in[19];
  const float* sv_lnb = (const float*)d_in[20];
  const float* en_W1  = (const float*)d_in[21];
  const float* en_b1  = (const float*)d_in[22];
  const float* en_Wc  = (const float*)d_in[23];
  const float* en_W2  = (const float*)d_in[24];
  const float* en_b2  = (const float*)d_in[25];
  const float* en_Wg  = (const float*)d_in[26];
  const float* en_bg  = (const float*)d_in[27];
  const float* en_lng = (const float*)d_in[28];
  const float* en_lnb = (const float*)d_in[29];
  const float* Wq     = (const float*)d_in[30];
  const float* Wk     = (const float*)d_in[31];
  const float* Wv     = (const float*)d_in[32];
  const float* Wo     = (const float*)d_in[33];

  // -------- workspace layout (bytes) --------
  static constexpr size_t OFF_FGW1T  = 0;                         // 256x3072 bf16
  static constexpr size_t OFF_FGW2T  = OFF_FGW1T  + 1572864;      // 256x256 bf16
  static constexpr size_t OFF_FGWGPT = OFF_FGW2T  + 131072;       // 128x256 bf16 (pad 24->128)
  static constexpr size_t OFF_BGPAD  = OFF_FGWGPT + 65536;        // 128 f32
  static constexpr size_t OFF_FGWSPT = OFF_BGPAD  + 512;          // 128x3072 bf16 (pad 12->128)
  static constexpr size_t OFF_BSPAD  = OFF_FGWSPT + 786432;       // 128 f32
  static constexpr size_t OFF_SVW1T  = OFF_BSPAD  + 512;          // 12x256x256 bf16
  static constexpr size_t OFF_SVW2T  = OFF_SVW1T  + 1572864;
  static constexpr size_t OFF_SVWGT  = OFF_SVW2T  + 1572864;      // 12x512x256 bf16
  static constexpr size_t OFF_ENW1T  = OFF_SVWGT  + 3145728;
  static constexpr size_t OFF_ENW2T  = OFF_ENW1T  + 131072;
  static constexpr size_t OFF_ENWGT  = OFF_ENW2T  + 131072;       // 512x256 bf16
  static constexpr size_t OFF_WQKVT  = OFF_ENWGT  + 262144;       // 640x256 bf16
  static constexpr size_t OFF_WOT    = OFF_WQKVT  + 327680;       // 256x64 bf16
  static constexpr size_t OFF_CVECFG = OFF_WOT    + 32768;        // 64x256 f32
  static constexpr size_t OFF_CVECEN = OFF_CVECFG + 65536;
  static constexpr size_t OFF_ARENA  = OFF_CVECEN + 65536;
  static constexpr size_t OFF_BUFA   = OFF_ARENA;                 // BT x 256 bf16
  static constexpr size_t OFF_BUFB   = OFF_BUFA + 12582912;       // BT x 256 bf16
  static constexpr size_t OFF_BUFG   = OFF_BUFB + 12582912;       // BT x 512 bf16
  static constexpr size_t OFF_GPAD   = OFF_BUFG + 25165824;       // BT x 128 bf16
  static constexpr size_t OFF_SKIPP  = OFF_GPAD + 6291456;        // BT x 128 bf16
  static constexpr size_t OFF_SEL    = OFF_SKIPP + 6291456;       // BT x 256 f32
  static constexpr size_t OFF_SELB   = OFF_SEL + 25165824;        // BT x 256 bf16
  static constexpr size_t OFF_SBUF   = OFF_ARENA;                 // overlay: 256x384x384 bf16 (75.5MB < 88MB dead arena head)
  static constexpr size_t OFF_GATED  = OFF_SELB + 12582912;       // BT x 12 f32
  static constexpr size_t OFF_WBUF   = OFF_GATED + 1179648;       // BT x 12 f32
  static constexpr size_t OFF_ENR    = OFF_WBUF + 1179648;        // BT x 256 bf16
  static constexpr size_t OFF_QKV    = OFF_ENR + 12582912;        // BT x 640 bf16
  static constexpr size_t OFF_PBAR   = OFF_QKV + 31457280;        // 64x384x384 bf16
  static constexpr size_t OFF_U      = OFF_PBAR + 18874368;       // BT x 256 bf16
  static constexpr size_t OFF_UT     = OFF_U + 12582912;          // 64x256x384 bf16
  static constexpr size_t WS_NEEDED  = OFF_UT + 12582912;         // ~192 MB

  if (ws_size < WS_NEEDED) return;  // fail cleanly (absmax == max|ref| signals this)

  char* ws = (char*)d_ws;
  bf16* fgW1T  = (bf16*)(ws + OFF_FGW1T);
  bf16* fgW2T  = (bf16*)(ws + OFF_FGW2T);
  bf16* fgWgPT = (bf16*)(ws + OFF_FGWGPT);
  float* bgPad = (float*)(ws + OFF_BGPAD);
  bf16* fgWsPT = (bf16*)(ws + OFF_FGWSPT);
  float* bsPad = (float*)(ws + OFF_BSPAD);
  bf16* svW1T  = (bf16*)(ws + OFF_SVW1T);
  bf16* svW2T  = (bf16*)(ws + OFF_SVW2T);
  bf16* svWgT  = (bf16*)(ws + OFF_SVWGT);
  bf16* enW1T  = (bf16*)(ws + OFF_ENW1T);
  bf16* enW2T  = (bf16*)(ws + OFF_ENW2T);
  bf16* enWgT  = (bf16*)(ws + OFF_ENWGT);
  bf16* WqkvT  = (bf16*)(ws + OFF_WQKVT);
  bf16* WoT    = (bf16*)(ws + OFF_WOT);
  float* cvecFg = (float*)(ws + OFF_CVECFG);
  float* cvecEn = (float*)(ws + OFF_CVECEN);
  bf16* BUFA   = (bf16*)(ws + OFF_BUFA);
  bf16* BUFB   = (bf16*)(ws + OFF_BUFB);
  bf16* BUFG   = (bf16*)(ws + OFF_BUFG);
  bf16* GPAD   = (bf16*)(ws + OFF_GPAD);
  bf16* SKIPP  = (bf16*)(ws + OFF_SKIPP);
  float* sel   = (float*)(ws + OFF_SEL);
  bf16* selb   = (bf16*)(ws + OFF_SELB);
  bf16* Sbuf   = (bf16*)(ws + OFF_SBUF);
  float* gated = (float*)(ws + OFF_GATED);
  float* wbuf  = (float*)(ws + OFF_WBUF);
  bf16* enr    = (bf16*)(ws + OFF_ENR);
  bf16* QKV    = (bf16*)(ws + OFF_QKV);
  bf16* Pbar   = (bf16*)(ws + OFF_PBAR);
  bf16* U      = (bf16*)(ws + OFF_U);
  bf16* UT     = (bf16*)(ws + OFF_UT);
  float* out   = (float*)d_out;

  // 1) weight prep (transpose + f32->bf16), one launch
  prep_kernel<<<19009, 256, 0, stream>>>(fg_W1, fg_W2, fg_Wg, fg_bg, fg_Ws, fg_bs,
                                         sv_W1, sv_W2, sv_Wg, en_W1, en_W2, en_Wg,
                                         Wq, Wk, Wv, Wo,
                                         fgW1T, fgW2T, fgWgPT, bgPad, fgWsPT, bsPad,
                                         svW1T, svW2T, svWgT, enW1T, enW2T, enWgT,
                                         WqkvT, WoT);
  // 2) context vectors (f32)
  cvec_kernel<<<dim3(64, 2), 256, 0, stream>>>(ctx, fg_Wc, en_Wc, cvecFg, cvecEn);

  // 3) flattened GRN (variable weights w)
  rungemm<EPI_BIAS|EPI_CVEC|EPI_ELU, true,  false>(stream, x, 3072, fgW1T, 3072, BUFA, 256, BTR, 256, 3072, fg_b1, cvecFg);
  rungemm<EPI_BIAS,                  false, false>(stream, BUFA, 256, fgW2T, 256, BUFB, 256, BTR, 256, 256, fg_b2);
  rungemm<EPI_BIAS,                  false, false>(stream, BUFB, 256, fgWgPT, 256, GPAD, 128, BTR, 128, 256, bgPad);
  gate12_kernel<<<1152, 256, 0, stream>>>(GPAD, gated);
  rungemm<EPI_BIAS,                  true,  false>(stream, x, 3072, fgWsPT, 3072, SKIPP, 128, BTR, 128, 3072, bsPad);
  lnsm12_kernel<<<96, 256, 0, stream>>>(SKIPP, gated, fg_lng, fg_lnb, wbuf);

  // 4) per-variable GRNs + weighted sum -> sel
  for (int v = 0; v < 12; ++v) {
    rungemm<EPI_BIAS|EPI_ELU, true,  false>(stream, x + v * 256, 3072, svW1T + v * 65536, 256, BUFA, 256, BTR, 256, 256, sv_b1 + v * 256);
    rungemm<EPI_BIAS,         false, false>(stream, BUFA, 256, svW2T + v * 65536, 256, BUFB, 256, BTR, 256, 256, sv_b2 + v * 256);
    rungemm<EPI_BIAS,         false, false>(stream, BUFB, 256, svWgT + (size_t)v * 131072, 256, BUFG, 512, BTR, 512, 256, sv_bg + v * 512);
    selacc_kernel<<<BTR, 256, 0, stream>>>(BUFG, x + v * 256, wbuf, sv_lng + v * 256, sv_lnb + v * 256,
                                           sel, selb, v, v == 11);
  }

  // 5) enrichment GRN
  rungemm<EPI_BIAS|EPI_CVEC|EPI_ELU, false, false>(stream, selb, 256, enW1T, 256, BUFA, 256, BTR, 256, 256, en_b1, cvecEn);
  rungemm<EPI_BIAS,                  false, false>(stream, BUFA, 256, enW2T, 256, BUFB, 256, BTR, 256, 256, en_b2);
  rungemm<EPI_BIAS,                  false, false>(stream, BUFB, 256, enWgT, 256, BUFG, 512, BTR, 512, 256, en_bg);
  enrln_kernel<<<BTR, 256, 0, stream>>>(BUFG, selb, en_lng, en_lnb, enr);

  // 6) attention: QKV = enr @ [Wq|Wk|Wv] (N padded 576->640)
  rungemm<0, false, false>(stream, enr, 256, WqkvT, 256, QKV, 640, BTR, 640, 256);
  // S[h,b] = Q K^T * 0.125 with causal mask, batched z = h*64+b
  rungemm<EPI_ATTN, false, false>(stream, QKV, 640, QKV + 256, 640, Sbuf, 384, 384, 384, 64,
                                  nullptr, nullptr, 256, 64, 64, 245760L, 64, 245760L, 147456L);
  softmax_avg_kernel<<<BTR, 384, 0, stream>>>(Sbuf, Pbar);
  // U = vp @ Wo  (mean-over-heads folded: out = Pbar @ (vp@Wo))
  rungemm<0, false, false>(stream, QKV + 512, 640, WoT, 64, U, 256, BTR, 256, 64);
  transpose_u_kernel<<<dim3(384, 64), 256, 0, stream>>>(U, UT);
  // out[b] = Pbar[b] @ U[b], batched over b -> f32 d_out
  rungemm<0, false, true>(stream, Pbar, 384, UT, 384, out, 256, 384, 256, 384,
                          nullptr, nullptr, 64, 1, 147456L, 0, 98304L, 0, 98304L);
}